// Round 3
// baseline (94.635 us; speedup 1.0000x reference)
//
#include <hip/hip_runtime.h>
#include <float.h>

#define D_DIM 1024
#define T_DIM 1024
#define B_DIM 16
#define NTOP 5
#define RAD 32              // exp(-k^2/8) == 0.0f in fp32 for |k| >= 29; 32 is safely exact
#define NORM_C 0.19947114f  // np.float32(1/(2*sqrt(2*pi)))
#define THRESH 2.2f         // c~Poisson(14.2); P(c<5)~1.5e-3/row -> ~25 fallback waves total
#define CAP 64              // fast path handles c<=64 (P(c>64) ~ 1e-20)

// Stage 1: one wave per row. Threshold-filter (all survivors positive -> raw
// float bits are a monotone u32 key), ballot-compact into wave-private LDS,
// then all-pairs rank via readlane over c<=64 u64 keys. Exact tie-break
// (lower index wins) via ~idx in the low 32 bits. Wave-uniform exact fallback
// (5-round masked butterfly) when c<5 or c>CAP.
__global__ __launch_bounds__(256) void topk5_kernel(const float* __restrict__ in,
                                                    int* __restrict__ idx_out) {
    const int wave = threadIdx.x >> 6;
    const int lane = threadIdx.x & 63;
    const int row  = blockIdx.x * 4 + wave;   // 0..16383

    const float4* row4 = (const float4*)(in + (size_t)row * D_DIM);

    float vv[16];
#pragma unroll
    for (int j = 0; j < 4; ++j) {
        float4 v = row4[lane + 64 * j];       // coalesced 16B/lane
        vv[4 * j + 0] = v.x; vv[4 * j + 1] = v.y;
        vv[4 * j + 2] = v.z; vv[4 * j + 3] = v.w;
    }

    __shared__ unsigned long long cand[4][CAP];

    const unsigned int lane4 = 4u * (unsigned int)lane;

    // --- filter + ballot compaction (skip element-positions with no hits) ---
    unsigned int base = 0;
#pragma unroll
    for (int k = 0; k < 16; ++k) {
        bool p = vv[k] > THRESH;
        unsigned long long m = __ballot(p);
        if (m) {                              // wave-uniform skip
            if (p) {
                unsigned int off = base +
                    __builtin_amdgcn_mbcnt_hi((unsigned int)(m >> 32),
                        __builtin_amdgcn_mbcnt_lo((unsigned int)m, 0));
                unsigned int e = lane4 + (unsigned int)(256 * (k >> 2) + (k & 3));
                unsigned long long key =
                    ((unsigned long long)__float_as_uint(vv[k]) << 32) | (unsigned int)~e;
                if (off < CAP) cand[wave][off] = key;
            }
            base += (unsigned int)__popcll(m);
        }
    }
    const int c = (int)base;
    __threadfence_block();   // order LDS writes before wave-local reads

    if (c >= NTOP && c <= CAP) {
        // --- fast path: all-pairs rank among c candidates (readlane bcast) ---
        unsigned long long mykey = (lane < c) ? cand[wave][lane] : 0ULL;
        const unsigned int mylo = (unsigned int)mykey;
        const unsigned int myhi = (unsigned int)(mykey >> 32);
        int rank = 0;
        for (int i = 0; i < c; ++i) {
            unsigned int blo = __builtin_amdgcn_readlane(mylo, i);
            unsigned int bhi = __builtin_amdgcn_readlane(myhi, i);
            unsigned long long bk = ((unsigned long long)bhi << 32) | blo;
            rank += (bk > mykey) ? 1 : 0;
        }
        if (lane < c && rank < NTOP) {
            unsigned int e = ~(unsigned int)mykey;
            idx_out[row * NTOP + rank] = (int)e;
        }
    } else {
        // --- fallback: exact 5-round masked butterfly ---
        int eidx[16];
#pragma unroll
        for (int k = 0; k < 16; ++k) eidx[k] = 4 * (lane + 64 * (k >> 2)) + (k & 3);
        int chosen[NTOP];
#pragma unroll
        for (int it = 0; it < NTOP; ++it) {
            float bv = -FLT_MAX; int bi = 0x7fffffff;
#pragma unroll
            for (int k = 0; k < 16; ++k)
                if (vv[k] > bv) { bv = vv[k]; bi = eidx[k]; }
#pragma unroll
            for (int s = 1; s < 64; s <<= 1) {
                float ov = __shfl_xor(bv, s);
                int   oi = __shfl_xor(bi, s);
                if (ov > bv || (ov == bv && oi < bi)) { bv = ov; bi = oi; }
            }
            chosen[it] = bi;
#pragma unroll
            for (int k = 0; k < 16; ++k)
                if (eidx[k] == bi) vv[k] = -FLT_MAX;
        }
        if (lane < NTOP) idx_out[row * NTOP + lane] = chosen[lane];
    }
}

// Stage 2: 4 blocks per output row b; each block covers 256 outputs with a
// 320-bin windowed LDS histogram, then convolves with the truncated Gaussian.
__global__ __launch_bounds__(256) void conv_kernel(const int* __restrict__ idx_in,
                                                   float* __restrict__ out) {
    const int b   = blockIdx.x >> 2;          // 0..15
    const int d0  = (blockIdx.x & 3) * 256;   // output slice start
    const int tid = threadIdx.x;

    __shared__ float hist[256 + 2 * RAD];     // bin 0 <-> pos = d0 - RAD
    __shared__ float w[2 * RAD + 1];

    hist[tid] = 0.0f;
    if (tid < 2 * RAD) hist[256 + tid] = 0.0f;
    if (tid < 2 * RAD + 1) {
        int k = tid - RAD;
        w[tid] = NORM_C * expf(-0.125f * (float)(k * k));
    }
    __syncthreads();

    // gather: indices for row b are at (b2*T_DIM + 64*b)*NTOP + r, r in [0,320)
    // per b2; 320 ints = 80 int4.
    for (int i = tid; i < B_DIM * 80; i += 256) {
        int b2 = i / 80;
        int r4 = i % 80;
        const int4* p = (const int4*)(idx_in + ((size_t)b2 * T_DIM + 64 * b) * NTOP);
        int4 pos = p[r4];
        unsigned int l0 = (unsigned int)(pos.x - d0 + RAD);
        unsigned int l1 = (unsigned int)(pos.y - d0 + RAD);
        unsigned int l2 = (unsigned int)(pos.z - d0 + RAD);
        unsigned int l3 = (unsigned int)(pos.w - d0 + RAD);
        if (l0 < 256 + 2 * RAD) atomicAdd(&hist[l0], 1.0f);
        if (l1 < 256 + 2 * RAD) atomicAdd(&hist[l1], 1.0f);
        if (l2 < 256 + 2 * RAD) atomicAdd(&hist[l2], 1.0f);
        if (l3 < 256 + 2 * RAD) atomicAdd(&hist[l3], 1.0f);
    }
    __syncthreads();

    // out[b, d0+tid] = sum_k hist[tid+k] * w[k]  (diff = RAD - k, exact)
    float acc = 0.0f;
    for (int k = 0; k <= 2 * RAD; ++k)
        acc += hist[tid + k] * w[k];
    out[(size_t)b * D_DIM + d0 + tid] = acc;
}

extern "C" void kernel_launch(void* const* d_in, const int* in_sizes, int n_in,
                              void* d_out, int out_size, void* d_ws, size_t ws_size,
                              hipStream_t stream) {
    const float* in  = (const float*)d_in[0];
    float*       out = (float*)d_out;
    int*         idx = (int*)d_ws;   // 16384*5 ints = 320 KB

    topk5_kernel<<<(B_DIM * T_DIM) / 4, 256, 0, stream>>>(in, idx);
    conv_kernel<<<B_DIM * 4, 256, 0, stream>>>(idx, out);
}